// Round 16
// baseline (145.710 us; speedup 1.0000x reference)
//
#include <hip/hip_runtime.h>
#include <hip/hip_bf16.h>

#define DI __device__ __forceinline__

typedef __bf16 bf16x8 __attribute__((ext_vector_type(8)));
typedef float f32x4 __attribute__((ext_vector_type(4)));

typedef const void __attribute__((address_space(1))) gas_t;
typedef void __attribute__((address_space(3))) las_t;

DI unsigned short f2bf(float f) {
    unsigned u = __builtin_bit_cast(unsigned, f);
    u += 0x7fffu + ((u >> 16) & 1u);   // RNE
    return (unsigned short)(u >> 16);
}

// ------- staging (256-thr GEMM): tile (ROWS x 64 k bf16) -> LDS via LDS-DMA -
template <int ROWS>
DI void stage_tile(const unsigned short* __restrict__ g, int ldK,
                   unsigned short* lds, int t) {
    int row_in = t >> 3;
    int kg = (t & 7) ^ (row_in & 7);
    const unsigned short* src = g + (size_t)row_in * ldK + kg * 8;
    unsigned short* dst = lds + ((t >> 6) << 9);
#pragma unroll
    for (int c = 0; c < ROWS / 32; ++c) {
        __builtin_amdgcn_global_load_lds(
            (gas_t*)(unsigned long long)(src + (size_t)c * 32 * ldK),
            (las_t*)(unsigned)(unsigned long long)(dst + c * 2048),
            16, 0, 0);
    }
}

// ------- staging (512-thr flash): 64 rows x 64 k per call --------------------
DI void stage64(const unsigned short* __restrict__ g, int ldK,
                unsigned short* lds, int t) {
    int row = t >> 3;                           // 0..63
    int kg = (t & 7) ^ (row & 7);
    __builtin_amdgcn_global_load_lds(
        (gas_t*)(unsigned long long)(g + (size_t)row * ldK + kg * 8),
        (las_t*)(unsigned)(unsigned long long)(lds + ((t >> 6) << 9)),
        16, 0, 0);
}

DI bf16x8 frag(const unsigned short* lds, int r, int kg) {
    return *(const bf16x8*)((const char*)lds + r * 128 + ((kg ^ (r & 7)) << 4));
}

template <int MR>
DI void compute_step(const unsigned short* As_, const unsigned short* Bs_,
                     f32x4 (&acc)[MR][4], int wm, int wn, int l15, int lks) {
#pragma unroll
    for (int kk = 0; kk < 2; ++kk) {
        bf16x8 a_[MR], b_[4];
#pragma unroll
        for (int m = 0; m < MR; ++m) a_[m] = frag(As_, wm + m * 16 + l15, kk * 4 + lks);
#pragma unroll
        for (int n = 0; n < 4; ++n) b_[n] = frag(Bs_, wn + n * 16 + l15, kk * 4 + lks);
#pragma unroll
        for (int m = 0; m < MR; ++m)
#pragma unroll
            for (int n = 0; n < 4; ++n)
                acc[m][n] = __builtin_amdgcn_mfma_f32_16x16x32_bf16(a_[m], b_[n], acc[m][n], 0, 0, 0);
    }
}

// ---------------- flash attention v4 ----------------------------------------
// vs v3 (r15): V LDS buffer DELETED (fragments load direct from global vN —
// natural [c][j] layout IS the B-fragment layout, lazy 2x16-VGPR halves);
// LDS 135.5 -> 68.5 KB -> 2 blocks/CU; QK accumulator split into 2 chains.
__global__ __launch_bounds__(512, 4) void attn_flash(
        const unsigned short* __restrict__ qT, const unsigned short* __restrict__ kT,
        const unsigned short* __restrict__ vN, unsigned short* __restrict__ OT) {
    __shared__ __align__(16) unsigned short Kb[8][4096];   // 64KB
    __shared__ __align__(16) unsigned short Ps[2048];      // 4KB: P[32 i][64 j] swizzled
    __shared__ float red[4][32];
    const int bx = blockIdx.x, t = threadIdx.x;
    const int b = bx & 7;                      // batch -> XCD
    const int i0 = (bx >> 3) << 5;             // 32 i-rows per block
    const int lane = t & 63, w = t >> 6;       // 8 waves
    const int l15 = lane & 15, lks = lane >> 4, rbase = lks * 4;
    const int iq = w & 1, jq = w >> 1;         // QK tile (iq, jq)
    const size_t sH = (size_t)1024 * 512;
    const unsigned short* Qg = qT + sH * b;
    const unsigned short* Kg = kT + sH * b;
    const unsigned short* Vg = vN + sH * b;
    const float scale = 0.044194173824159216f;

    // Q -> registers: rows i0 + iq*16 + l15, all 512 k (16 chunks of 32)
    bf16x8 q[16];
    {
        const unsigned short* qrow = Qg + (size_t)(i0 + iq * 16 + l15) * 512 + lks * 8;
#pragma unroll
        for (int kk = 0; kk < 16; ++kk) q[kk] = *(const bf16x8*)(qrow + kk * 32);
    }
    // V fragment base for this wave: c = w*64 + cq*16 + l15
    const unsigned short* vrow = Vg + (size_t)(w * 64 + l15) * 1024;

    f32x4 oacc[2][4];
#pragma unroll
    for (int m = 0; m < 2; ++m)
#pragma unroll
        for (int cq = 0; cq < 4; ++cq) oacc[m][cq] = (f32x4){0.f, 0.f, 0.f, 0.f};
    float rs[4] = {0.f, 0.f, 0.f, 0.f};

    // prologue: stage K tile for j0 = 0
#pragma unroll
    for (int cc = 0; cc < 8; ++cc)
        stage64(Kg + cc * 64, 512, &Kb[cc][0], t);
    asm volatile("s_waitcnt vmcnt(0)" ::: "memory");
    __syncthreads();

    for (int j0 = 0; j0 < 1024; j0 += 64) {
        // V fragments, half 0 (k-slots lks): in flight under QK
        bf16x8 vf0[4];
#pragma unroll
        for (int cq = 0; cq < 4; ++cq)
            vf0[cq] = *(const bf16x8*)(vrow + (size_t)cq * 16 * 1024 + j0 + lks * 8);

        // QK^T: wave (iq,jq) -> 16i x 16j, K-depth 512, 2 interleaved chains
        f32x4 ea = (f32x4){0.f, 0.f, 0.f, 0.f};
        f32x4 eb = (f32x4){0.f, 0.f, 0.f, 0.f};
#pragma unroll
        for (int kc = 0; kc < 8; ++kc) {
            bf16x8 kf0 = frag(&Kb[kc][0], jq * 16 + l15, lks);
            bf16x8 kf1 = frag(&Kb[kc][0], jq * 16 + l15, 4 + lks);
            ea = __builtin_amdgcn_mfma_f32_16x16x32_bf16(q[kc * 2], kf0, ea, 0, 0, 0);
            eb = __builtin_amdgcn_mfma_f32_16x16x32_bf16(q[kc * 2 + 1], kf1, eb, 0, 0, 0);
        }
        f32x4 e4 = ea + eb;
        // exp -> Ps (swizzled), rowsum partials (16-lane reduce over j)
        const int jcol = jq * 16 + l15;
#pragma unroll
        for (int jr = 0; jr < 4; ++jr) {
            float e = __expf(e4[jr] * scale);
            int irow = iq * 16 + rbase + jr;
            *(unsigned short*)((char*)Ps + irow * 128 +
                (((jcol >> 3) ^ (irow & 7)) << 4) + ((jcol & 7) << 1)) = f2bf(e);
            float p = e;
            p += __shfl_xor(p, 1); p += __shfl_xor(p, 2);
            p += __shfl_xor(p, 4); p += __shfl_xor(p, 8);
            rs[jr] += p;
        }
        __syncthreads();                                   // A: Ps visible; Kb reads done

        // stage next K tile (lands while PV computes)
        if (j0 + 64 < 1024) {
#pragma unroll
            for (int cc = 0; cc < 8; ++cc)
                stage64(Kg + (size_t)(j0 + 64) * 512 + cc * 64, 512, &Kb[cc][0], t);
        }
        // V fragments, half 1 (k-slots 4+lks): in flight under PV half 0
        bf16x8 vf1[4];
#pragma unroll
        for (int cq = 0; cq < 4; ++cq)
            vf1[cq] = *(const bf16x8*)(vrow + (size_t)cq * 16 * 1024 + j0 + 32 + lks * 8);

        // PV: wave c-strip = w*64
#pragma unroll
        for (int cq = 0; cq < 4; ++cq) {
            bf16x8 pf0 = frag(Ps, l15, lks);
            bf16x8 pf1 = frag(Ps, 16 + l15, lks);
            oacc[0][cq] = __builtin_amdgcn_mfma_f32_16x16x32_bf16(pf0, vf0[cq], oacc[0][cq], 0, 0, 0);
            oacc[1][cq] = __builtin_amdgcn_mfma_f32_16x16x32_bf16(pf1, vf0[cq], oacc[1][cq], 0, 0, 0);
        }
#pragma unroll
        for (int cq = 0; cq < 4; ++cq) {
            bf16x8 pf0 = frag(Ps, l15, 4 + lks);
            bf16x8 pf1 = frag(Ps, 16 + l15, 4 + lks);
            oacc[0][cq] = __builtin_amdgcn_mfma_f32_16x16x32_bf16(pf0, vf1[cq], oacc[0][cq], 0, 0, 0);
            oacc[1][cq] = __builtin_amdgcn_mfma_f32_16x16x32_bf16(pf1, vf1[cq], oacc[1][cq], 0, 0, 0);
        }
        asm volatile("s_waitcnt vmcnt(0)" ::: "memory");   // K' landed
        __syncthreads();                                   // B: Ps reads done
    }

    // cross-wave rowsum reduce: red[jq][i]
    if (l15 == 0) {
#pragma unroll
        for (int jr = 0; jr < 4; ++jr)
            red[jq][iq * 16 + rbase + jr] = rs[jr];
    }
    __syncthreads();
    unsigned short* Ob = OT + sH * b;
#pragma unroll
    for (int m = 0; m < 2; ++m) {
#pragma unroll
        for (int jr = 0; jr < 4; ++jr) {
            int il = m * 16 + rbase + jr;
            float inv = 1.f / (red[0][il] + red[1][il] + red[2][il] + red[3][il]);
#pragma unroll
            for (int cq = 0; cq < 4; ++cq)
                Ob[(size_t)(i0 + il) * 512 + w * 64 + cq * 16 + l15] =
                    f2bf(oacc[m][cq][jr] * inv);
        }
    }
}

// ------------- GEMM phase: C[M,N] = A[M,K] * B[N,K]^T, tile TM x 128 --------
// MODE 0: QKV fused: region (row>>9): 0->qT C^T(+b0), 1->kT C^T(+b1),
//         2->vN natural(+b2)       [r6 form, proven]
// MODE 3: proj -> f32 C^T + bias[ng] + residual
template <int TM, int MODE, int PIPE>
DI void gemm_phase(unsigned short* AsB, unsigned short* BsB,
                   const unsigned short* __restrict__ A, const unsigned short* __restrict__ B,
                   const float* __restrict__ b0, const float* __restrict__ b1,
                   const float* __restrict__ b2,
                   void* __restrict__ C0, void* __restrict__ C1, void* __restrict__ C2,
                   const float* __restrict__ resid,
                   int M, int N, int K, size_t sA, size_t sB, size_t sC,
                   int bx, int t) {
    constexpr int MR = TM / 32;
    constexpr int ABUF = TM * 64;
    constexpr int BBUF = 128 * 64;
    int b = bx & 7;
    int tile = bx >> 3;
    int nTx = N >> 7;
    int tx = tile % nTx, ty = tile / nTx;
    int m0 = ty * TM, n0 = tx << 7;
    const unsigned short* Ag = A + sA * b + (size_t)m0 * K;
    const unsigned short* Bg = B + sB * b + (size_t)n0 * K;
    int lane = t & 63, wid = t >> 6;
    int wm = (wid >> 1) * (TM / 2), wn = (wid & 1) * 64;
    const int l15 = lane & 15, lks = lane >> 4;
    const int rbase = lks * 4;

    f32x4 acc[MR][4];
#pragma unroll
    for (int i = 0; i < MR; ++i)
#pragma unroll
        for (int j = 0; j < 4; ++j) acc[i][j] = (f32x4){0.f, 0.f, 0.f, 0.f};

    float bn4[4];
    if constexpr (MODE == 3) {
#pragma unroll
        for (int n = 0; n < 4; ++n) bn4[n] = b0[n0 + wn + n * 16 + l15];
    }

    if constexpr (PIPE == 0) {
        for (int k0 = 0; k0 < K; k0 += 64) {
            stage_tile<TM>(Ag + k0, K, AsB, t);
            stage_tile<128>(Bg + k0, K, BsB, t);
            asm volatile("s_waitcnt vmcnt(0)" ::: "memory");
            __syncthreads();
            compute_step<MR>(AsB, BsB, acc, wm, wn, l15, lks);
            __syncthreads();
        }
    } else {
        stage_tile<TM>(Ag, K, AsB, t);
        stage_tile<128>(Bg, K, BsB, t);
        asm volatile("s_waitcnt vmcnt(0)" ::: "memory");
        __syncthreads();
        int cur = 0;
        for (int k0 = 0; k0 < K; k0 += 64) {
            if (k0 + 64 < K) {
                stage_tile<TM>(Ag + k0 + 64, K, AsB + (cur ^ 1) * ABUF, t);
                stage_tile<128>(Bg + k0 + 64, K, BsB + (cur ^ 1) * BBUF, t);
            }
            compute_step<MR>(AsB + cur * ABUF, BsB + cur * BBUF, acc, wm, wn, l15, lks);
            if (k0 + 64 < K) {
                asm volatile("s_waitcnt vmcnt(0)" ::: "memory");
                __syncthreads();
            }
            cur ^= 1;
        }
    }

    const size_t cb = sC * b;
    if constexpr (MODE == 0) {
#pragma unroll
        for (int m = 0; m < MR; ++m) {
            int mgg = m0 + wm + m * 16 + rbase;
            int region = mgg >> 9;                  // 0=Q 1=K 2=V
            int local = mgg & 511;
            const float* bias = (region == 0) ? b0 : (region == 1) ? b1 : b2;
            float bv4[4];
#pragma unroll
            for (int j = 0; j < 4; ++j) bv4[j] = bias[local + j];
            if (region < 2) {
                unsigned short* Ct = (unsigned short*)(region == 0 ? C0 : C1) + cb;
#pragma unroll
                for (int n = 0; n < 4; ++n) {
                    int ng = n0 + wn + n * 16 + l15;
                    f32x4 v = acc[m][n];
                    ushort4 o;
                    o.x = f2bf(v[0] + bv4[0]); o.y = f2bf(v[1] + bv4[1]);
                    o.z = f2bf(v[2] + bv4[2]); o.w = f2bf(v[3] + bv4[3]);
                    *(ushort4*)&Ct[(size_t)ng * 512 + local] = o;
                }
            } else {
                unsigned short* Vb_ = (unsigned short*)C2 + cb;
#pragma unroll
                for (int n = 0; n < 4; ++n) {
                    int ng = n0 + wn + n * 16 + l15;
                    f32x4 v = acc[m][n];
#pragma unroll
                    for (int j = 0; j < 4; ++j)
                        Vb_[(size_t)(local + j) * 1024 + ng] = f2bf(v[j] + bv4[j]);
                }
            }
        }
    } else {
        float* Cf = (float*)C0 + cb;
#pragma unroll
        for (int m = 0; m < MR; ++m) {
            int mg = m0 + wm + m * 16 + rbase;
#pragma unroll
            for (int n = 0; n < 4; ++n) {
                int ng = n0 + wn + n * 16 + l15;
                f32x4 v = acc[m][n];
                const float* rp = resid + cb + (size_t)ng * M + mg;
                float4 o;
                o.x = v[0] + bn4[n] + rp[0]; o.y = v[1] + bn4[n] + rp[1];
                o.z = v[2] + bn4[n] + rp[2]; o.w = v[3] + bn4[n] + rp[3];
                *(float4*)&Cf[(size_t)ng * M + mg] = o;
            }
        }
    }
}

// ----------------- prep: GN stats + weight cvt ------------------------------
DI void stats_body(const float* __restrict__ x, float2* __restrict__ part,
                   float* red, int bx, int t) {
    int b = bx & 7, g = (bx >> 3) & 7, ch = bx >> 6;
    size_t base = ((size_t)b * 512 + g * 64 + ch * 8) * 1024;
    const float4* xp = (const float4*)(x + base);
    float s = 0.f, q = 0.f;
#pragma unroll
    for (int it = 0; it < 8; ++it) {
        float4 v = xp[it * 256 + t];
        s += (v.x + v.y) + (v.z + v.w);
        q += (v.x * v.x + v.y * v.y) + (v.z * v.z + v.w * v.w);
    }
#pragma unroll
    for (int o = 32; o; o >>= 1) { s += __shfl_xor(s, o); q += __shfl_xor(q, o); }
    int lane = t & 63, wid = t >> 6;
    if (!lane) { red[wid] = s; red[4 + wid] = q; }
    __syncthreads();
    if (t == 0)
        part[((b * 8 + g) * 8) + ch] =
            make_float2(red[0] + red[1] + red[2] + red[3],
                        red[4] + red[5] + red[6] + red[7]);
}

__global__ __launch_bounds__(256) void prep_kernel(const float* __restrict__ x,
                                                   float2* __restrict__ part,
                                                   const float* __restrict__ w0,
                                                   const float* __restrict__ w1,
                                                   const float* __restrict__ w2,
                                                   const float* __restrict__ w3,
                                                   unsigned short* __restrict__ wb) {
    __shared__ float red[8];
    int bx = blockIdx.x, t = threadIdx.x;
    if (bx < 512) {
        stats_body(x, part, red, bx, t);
    } else {
        int chunk = bx - 512;
        int w = chunk >> 8;
        const float* sp = (w == 0) ? w0 : (w == 1) ? w1 : (w == 2) ? w2 : w3;
        unsigned short* o = wb + (size_t)w * 262144;
        int idx = (chunk & 255) * 256 + t;
        float4 v = ((const float4*)sp)[idx];
        ushort4 r;
        r.x = f2bf(v.x); r.y = f2bf(v.y); r.z = f2bf(v.z); r.w = f2bf(v.w);
        ((ushort4*)o)[idx] = r;
    }
}

// -------- GN apply + transposed write: x[b,c,hw] f32 -> hT[b,hw,c] bf16 -----
__global__ __launch_bounds__(256) void gn_applyT(const float* __restrict__ x,
                                                 const float2* __restrict__ part,
                                                 const float* __restrict__ gs,
                                                 const float* __restrict__ gb,
                                                 unsigned short* __restrict__ hT) {
    __shared__ unsigned short tile[128 * 66];
    int bx = blockIdx.x, t = threadIdx.x;
    int b = bx & 7, g = (bx >> 3) & 7, ic = bx >> 6;
    int bg = b * 8 + g;
    float s = 0.f, q = 0.f;
#pragma unroll
    for (int k = 0; k < 8; ++k) { float2 p = part[bg * 8 + k]; s += p.x; q += p.y; }
    float mean = s * (1.f / 65536.f);
    float var = q * (1.f / 65536.f) - mean * mean;
    float rstd = rsqrtf(var + 1e-5f);

    int i4 = t & 31, cq = t >> 5;
    size_t xbase = ((size_t)b * 512 + g * 64) * 1024 + ic * 128;
#pragma unroll
    for (int pass = 0; pass < 8; ++pass) {
        int c = pass * 8 + cq;
        float4 v = *(const float4*)&x[xbase + (size_t)c * 1024 + i4 * 4];
        int gc = g * 64 + c;
        float sc = gs[gc] * rstd, bi = gb[gc] - mean * sc;
        unsigned short* tp = &tile[(i4 * 4) * 66 + c];
        tp[0]   = f2bf(v.x * sc + bi);
        tp[66]  = f2bf(v.y * sc + bi);
        tp[132] = f2bf(v.z * sc + bi);
        tp[198] = f2bf(v.w * sc + bi);
    }
    __syncthreads();
    int i = t >> 1, h = t & 1;
    const unsigned short* tp2 = &tile[i * 66 + h * 32];
    unsigned short* op = &hT[(size_t)b * (1024 * 512) + (size_t)(ic * 128 + i) * 512 + g * 64 + h * 32];
#pragma unroll
    for (int cc = 0; cc < 4; ++cc) {
        unsigned short tmp[8];
#pragma unroll
        for (int j = 0; j < 8; ++j) tmp[j] = tp2[cc * 8 + j];
        *(uint4*)&op[cc * 8] = *(const uint4*)tmp;
    }
}

template <int TM, int MODE, int MINW, int PIPE>
__global__ __launch_bounds__(256, MINW) void gemm_bt(
        const unsigned short* __restrict__ A, const unsigned short* __restrict__ B,
        const float* __restrict__ b0, const float* __restrict__ b1,
        const float* __restrict__ b2,
        void* __restrict__ C0, void* __restrict__ C1, void* __restrict__ C2,
        const float* __restrict__ resid,
        int M, int N, int K, size_t sA, size_t sB, size_t sC) {
    constexpr int NBUF = PIPE ? 2 : 1;
    __shared__ __align__(16) unsigned short As[NBUF * TM * 64];
    __shared__ __align__(16) unsigned short Bs[NBUF * 128 * 64];
    gemm_phase<TM, MODE, PIPE>(As, Bs, A, B, b0, b1, b2, C0, C1, C2, resid,
                               M, N, K, sA, sB, sC, blockIdx.x, threadIdx.x);
}

extern "C" void kernel_launch(void* const* d_in, const int* in_sizes, int n_in,
                              void* d_out, int out_size, void* d_ws, size_t ws_size,
                              hipStream_t stream) {
    const float* x  = (const float*)d_in[0];
    const float* gs = (const float*)d_in[1];
    const float* gb = (const float*)d_in[2];
    const float* wq = (const float*)d_in[3];
    const float* bq = (const float*)d_in[4];
    const float* wk = (const float*)d_in[5];
    const float* bk = (const float*)d_in[6];
    const float* wv = (const float*)d_in[7];
    const float* bv = (const float*)d_in[8];
    const float* wp = (const float*)d_in[9];
    const float* bp = (const float*)d_in[10];
    float* out = (float*)d_out;

    char* ws = (char*)d_ws;
    const size_t MB = 1u << 20;
    unsigned short* hT = (unsigned short*)(ws + 0);         // [b][1024][512]
    unsigned short* wb = (unsigned short*)(ws + 8 * MB);    // [wq;wk;wv;wp] bf16
    unsigned short* qT = (unsigned short*)(ws + 10 * MB);   // [b][1024][512]
    unsigned short* kT = (unsigned short*)(ws + 18 * MB);   // [b][1024][512]
    unsigned short* vN = (unsigned short*)(ws + 26 * MB);   // [b][512][1024]
    unsigned short* OT = (unsigned short*)(ws + 34 * MB);   // [b][1024][512] normalized
    float2* gnpart     = (float2*)(ws + 42 * MB);           // 512 x float2

    const unsigned short* wpb = wb + 3 * 262144;
    const size_t sH = 1024 * 512;

    prep_kernel<<<1536, 256, 0, stream>>>(x, gnpart, wq, wk, wv, wp, wb);
    gn_applyT<<<512, 256, 0, stream>>>(x, gnpart, gs, gb, hT);

    // QKV fused (r6 form): TM=128, 1-phase, 768 blocks = exactly 3/CU.
    gemm_bt<128, 0, 3, 0><<<768, 256, 0, stream>>>(
        wb, hT, bq, bk, bv, qT, kT, vN, nullptr,
        1536, 1024, 512, 0, sH, sH);
    // flash attention v4: 256 blocks x 512 threads, 68.5KB LDS (2 blocks/CU),
    // V direct-to-reg, split QK chains, 1 drain/iter.
    attn_flash<<<256, 512, 0, stream>>>(qT, kT, vN, OT);
    // proj (r6 form): A=OT, B=Wp -> out[b][c][i] f32 (C^T) + bias[c] + resid
    gemm_bt<64, 3, 2, 1><<<512, 256, 0, stream>>>(
        OT, wpb, bp, nullptr, nullptr, out, nullptr, nullptr, x,
        1024, 512, 512, sH, 0, sH);
}

// Round 17
// 75.272 us; speedup vs baseline: 1.9358x; 1.9358x over previous
//
#include <hip/hip_runtime.h>
#include <hip/hip_bf16.h>

#define DI __device__ __forceinline__

typedef __bf16 bf16x8 __attribute__((ext_vector_type(8)));
typedef float f32x4 __attribute__((ext_vector_type(4)));

typedef const void __attribute__((address_space(1))) gas_t;
typedef void __attribute__((address_space(3))) las_t;

DI unsigned short f2bf(float f) {
    unsigned u = __builtin_bit_cast(unsigned, f);
    u += 0x7fffu + ((u >> 16) & 1u);   // RNE
    return (unsigned short)(u >> 16);
}

// ------- staging: global tile (ROWS x 64 k bf16) -> LDS via LDS-DMA ---------
template <int ROWS>
DI void stage_tile(const unsigned short* __restrict__ g, int ldK,
                   unsigned short* lds, int t) {
    int row_in = t >> 3;
    int kg = (t & 7) ^ (row_in & 7);
    const unsigned short* src = g + (size_t)row_in * ldK + kg * 8;
    unsigned short* dst = lds + ((t >> 6) << 9);
#pragma unroll
    for (int c = 0; c < ROWS / 32; ++c) {
        __builtin_amdgcn_global_load_lds(
            (gas_t*)(unsigned long long)(src + (size_t)c * 32 * ldK),
            (las_t*)(unsigned)(unsigned long long)(dst + c * 2048),
            16, 0, 0);
    }
}

DI bf16x8 frag(const unsigned short* lds, int r, int kg) {
    return *(const bf16x8*)((const char*)lds + r * 128 + ((kg ^ (r & 7)) << 4));
}

template <int MR>
DI void compute_step(const unsigned short* As_, const unsigned short* Bs_,
                     f32x4 (&acc)[MR][4], int wm, int wn, int l15, int lks) {
#pragma unroll
    for (int kk = 0; kk < 2; ++kk) {
        bf16x8 a_[MR], b_[4];
#pragma unroll
        for (int m = 0; m < MR; ++m) a_[m] = frag(As_, wm + m * 16 + l15, kk * 4 + lks);
#pragma unroll
        for (int n = 0; n < 4; ++n) b_[n] = frag(Bs_, wn + n * 16 + l15, kk * 4 + lks);
#pragma unroll
        for (int m = 0; m < MR; ++m)
#pragma unroll
            for (int n = 0; n < 4; ++n)
                acc[m][n] = __builtin_amdgcn_mfma_f32_16x16x32_bf16(a_[m], b_[n], acc[m][n], 0, 0, 0);
    }
}

// ---- wave-private 64x64 LDS re-tile (8KB, XOR-swizzled 16B chunks) ---------
// purpose: convert fragment-scattered output into FULL-LINE 64-lane stores
DI void rt_put4(unsigned short* rt, int row, int col, ushort4 v) {
    *(ushort4*)((char*)rt + row * 128 + (((col >> 3) ^ (row & 7)) << 4) + ((col & 7) << 1)) = v;
}
DI void rt_put1(unsigned short* rt, int row, int col, unsigned short v) {
    *(unsigned short*)((char*)rt + row * 128 + (((col >> 3) ^ (row & 7)) << 4) + ((col & 7) << 1)) = v;
}
DI void rt_flush(const unsigned short* rt, unsigned short* gdst, size_t gstride, int lane) {
    int r = lane >> 3, g = lane & 7;
#pragma unroll
    for (int rr = 0; rr < 8; ++rr) {
        int row = rr * 8 + r;
        uint4 v = *(const uint4*)((const char*)rt + row * 128 + ((g ^ (row & 7)) << 4));
        *(uint4*)&gdst[(size_t)row * gstride + g * 8] = v;   // 64 lanes: 8 rows x 128B
    }
}

// ------------- GEMM phase: C[M,N] = A[M,K] * B[N,K]^T, tile TM x 128 --------
// MODE 0: QKV fused (TM=128): region = m0>>9 (block-uniform): 0->qT C^T(+b0),
//         1->kT C^T(+b1), 2->vN natural(+b2). All via full-line re-tile flush.
//         Dispatch order remapped V->K->Q (qT/kT freshest in L2 for scores).
// MODE 1: scores A=qT,B=kT -> E[i][j]=exp(acc*scale) natural, re-tile flush
//         + row sums (16-lane reduce) -> spart[b][16][i]
// MODE 2: PV (A=vN, B=E) -> bf16 C^T scaled by 1/rowsum (spart by i, 16 parts)
// MODE 3: proj -> f32 C^T + bias[ng] + residual
template <int TM, int MODE, int PIPE>
DI void gemm_phase(unsigned short* AsB, unsigned short* BsB,
                   const unsigned short* __restrict__ A, const unsigned short* __restrict__ B,
                   const float* __restrict__ b0, const float* __restrict__ b1,
                   const float* __restrict__ b2,
                   void* __restrict__ C0, void* __restrict__ C1, void* __restrict__ C2,
                   const float* __restrict__ resid, float* __restrict__ spart,
                   int M, int N, int K, float scale, size_t sA, size_t sB, size_t sC,
                   int bx, int t) {
    constexpr int MR = TM / 32;
    constexpr int ABUF = TM * 64;
    constexpr int BBUF = 128 * 64;
    int b = bx & 7;
    int tile = bx >> 3;
    int nTx = N >> 7;
    int tx = tile % nTx, ty = tile / nTx;
    if constexpr (MODE == 0) ty = 11 - ty;   // V tiles first, Q last (L2 freshness)
    int m0 = ty * TM, n0 = tx << 7;
    const unsigned short* Ag = A + sA * b + (size_t)m0 * K;
    const unsigned short* Bg = B + sB * b + (size_t)n0 * K;
    int lane = t & 63, wid = t >> 6;
    int wm = (wid >> 1) * (TM / 2), wn = (wid & 1) * 64;
    const int l15 = lane & 15, lks = lane >> 4;
    const int rbase = lks * 4;

    f32x4 acc[MR][4];
#pragma unroll
    for (int i = 0; i < MR; ++i)
#pragma unroll
        for (int j = 0; j < 4; ++j) acc[i][j] = (f32x4){0.f, 0.f, 0.f, 0.f};

    float inv[4];
    if constexpr (MODE == 2) {
#pragma unroll
        for (int n = 0; n < 4; ++n) {
            int ng = n0 + wn + n * 16 + l15;
            float ssum = 0.f;
#pragma unroll
            for (int k = 0; k < 16; ++k) ssum += spart[(size_t)(b * 16 + k) * 1024 + ng];
            inv[n] = 1.f / ssum;
        }
    }
    float bn4[4];
    if constexpr (MODE == 3) {
#pragma unroll
        for (int n = 0; n < 4; ++n) bn4[n] = b0[n0 + wn + n * 16 + l15];
    }

    if constexpr (PIPE == 0) {
        for (int k0 = 0; k0 < K; k0 += 64) {
            stage_tile<TM>(Ag + k0, K, AsB, t);
            stage_tile<128>(Bg + k0, K, BsB, t);
            asm volatile("s_waitcnt vmcnt(0)" ::: "memory");
            __syncthreads();
            compute_step<MR>(AsB, BsB, acc, wm, wn, l15, lks);
            __syncthreads();
        }
    } else {
        stage_tile<TM>(Ag, K, AsB, t);
        stage_tile<128>(Bg, K, BsB, t);
        asm volatile("s_waitcnt vmcnt(0)" ::: "memory");
        __syncthreads();
        int cur = 0;
        for (int k0 = 0; k0 < K; k0 += 64) {
            if (k0 + 64 < K) {
                stage_tile<TM>(Ag + k0 + 64, K, AsB + (cur ^ 1) * ABUF, t);
                stage_tile<128>(Bg + k0 + 64, K, BsB + (cur ^ 1) * BBUF, t);
            }
            compute_step<MR>(AsB + cur * ABUF, BsB + cur * BBUF, acc, wm, wn, l15, lks);
            if (k0 + 64 < K) {
                asm volatile("s_waitcnt vmcnt(0)" ::: "memory");
                __syncthreads();
            }
            cur ^= 1;
        }
    }

    const size_t cb = sC * b;
    if constexpr (MODE == 0) {
        __syncthreads();   // As/Bs reads done; reuse as re-tile buffers
        unsigned short* rt = (wid < 2) ? (AsB + wid * 4096) : (BsB + (wid - 2) * 4096);
        int region = m0 >> 9;                   // block-uniform (TM=128 | 512)
        int local0 = m0 & 511;
        if (region < 2) {
            const float* bias = (region == 0) ? b0 : b1;
#pragma unroll
            for (int m = 0; m < MR; ++m) {
                int cl = m * 16 + rbase;
                float bv4[4];
#pragma unroll
                for (int j = 0; j < 4; ++j) bv4[j] = bias[local0 + wm + cl + j];
#pragma unroll
                for (int n = 0; n < 4; ++n) {
                    f32x4 v = acc[m][n];
                    ushort4 o;
                    o.x = f2bf(v[0] + bv4[0]); o.y = f2bf(v[1] + bv4[1]);
                    o.z = f2bf(v[2] + bv4[2]); o.w = f2bf(v[3] + bv4[3]);
                    rt_put4(rt, n * 16 + l15, cl, o);
                }
            }
            unsigned short* Ct = (unsigned short*)(region == 0 ? C0 : C1) + cb
                                 + (size_t)(n0 + wn) * 512 + local0 + wm;
            rt_flush(rt, Ct, 512, lane);
        } else {
#pragma unroll
            for (int m = 0; m < MR; ++m) {
                float bv4[4];
#pragma unroll
                for (int j = 0; j < 4; ++j) bv4[j] = b2[local0 + wm + m * 16 + rbase + j];
#pragma unroll
                for (int n = 0; n < 4; ++n) {
                    int cl = n * 16 + l15;
                    f32x4 v = acc[m][n];
#pragma unroll
                    for (int j = 0; j < 4; ++j)
                        rt_put1(rt, m * 16 + rbase + j, cl, f2bf(v[j] + bv4[j]));
                }
            }
            unsigned short* Vb = (unsigned short*)C2 + cb
                                 + (size_t)(local0 + wm) * 1024 + (n0 + wn);
            rt_flush(rt, Vb, 1024, lane);
        }
    } else if constexpr (MODE == 1) {
        __syncthreads();
        unsigned short* rt = AsB + wid * 4096;   // PIPE=1: As = 32KB, 4 waves
        int part = tx * 2 + (wid & 1);           // 16 parts of 64 j's
#pragma unroll
        for (int m = 0; m < MR; ++m) {
            float ps[4] = {0.f, 0.f, 0.f, 0.f};
#pragma unroll
            for (int n = 0; n < 4; ++n) {
                int jl = n * 16 + l15;
                f32x4 v = acc[m][n];
#pragma unroll
                for (int jr = 0; jr < 4; ++jr) {
                    float e = __expf(v[jr] * scale);
                    ps[jr] += e;
                    rt_put1(rt, m * 16 + rbase + jr, jl, f2bf(e));
                }
            }
#pragma unroll
            for (int jr = 0; jr < 4; ++jr) {
                float p = ps[jr];
                p += __shfl_xor(p, 1); p += __shfl_xor(p, 2);
                p += __shfl_xor(p, 4); p += __shfl_xor(p, 8);
                if (l15 == 0) {
                    int row = m0 + wm + m * 16 + rbase + jr;
                    spart[(size_t)(b * 16 + part) * 1024 + row] = p;
                }
            }
        }
        unsigned short* Eb = (unsigned short*)C0 + cb
                             + (size_t)(m0 + wm) * 1024 + (n0 + wn);
        rt_flush(rt, Eb, 1024, lane);
    } else if constexpr (MODE == 2) {
        unsigned short* Ct = (unsigned short*)C0 + cb;
#pragma unroll
        for (int m = 0; m < MR; ++m) {
            int mg = m0 + wm + m * 16 + rbase;
#pragma unroll
            for (int n = 0; n < 4; ++n) {
                int ng = n0 + wn + n * 16 + l15;
                f32x4 v = acc[m][n];
                ushort4 o;
                o.x = f2bf(v[0] * inv[n]); o.y = f2bf(v[1] * inv[n]);
                o.z = f2bf(v[2] * inv[n]); o.w = f2bf(v[3] * inv[n]);
                *(ushort4*)&Ct[(size_t)ng * M + mg] = o;
            }
        }
    } else {
        float* Cf = (float*)C0 + cb;
#pragma unroll
        for (int m = 0; m < MR; ++m) {
            int mg = m0 + wm + m * 16 + rbase;
#pragma unroll
            for (int n = 0; n < 4; ++n) {
                int ng = n0 + wn + n * 16 + l15;
                f32x4 v = acc[m][n];
                const float* rp = resid + cb + (size_t)ng * M + mg;
                float4 o;
                o.x = v[0] + bn4[n] + rp[0]; o.y = v[1] + bn4[n] + rp[1];
                o.z = v[2] + bn4[n] + rp[2]; o.w = v[3] + bn4[n] + rp[3];
                *(float4*)&Cf[(size_t)ng * M + mg] = o;
            }
        }
    }
}

// ----------------- prep: GN stats + weight cvt ------------------------------
DI void stats_body(const float* __restrict__ x, float2* __restrict__ part,
                   float* red, int bx, int t) {
    int b = bx & 7, g = (bx >> 3) & 7, ch = bx >> 6;
    size_t base = ((size_t)b * 512 + g * 64 + ch * 8) * 1024;
    const float4* xp = (const float4*)(x + base);
    float s = 0.f, q = 0.f;
#pragma unroll
    for (int it = 0; it < 8; ++it) {
        float4 v = xp[it * 256 + t];
        s += (v.x + v.y) + (v.z + v.w);
        q += (v.x * v.x + v.y * v.y) + (v.z * v.z + v.w * v.w);
    }
#pragma unroll
    for (int o = 32; o; o >>= 1) { s += __shfl_xor(s, o); q += __shfl_xor(q, o); }
    int lane = t & 63, wid = t >> 6;
    if (!lane) { red[wid] = s; red[4 + wid] = q; }
    __syncthreads();
    if (t == 0)
        part[((b * 8 + g) * 8) + ch] =
            make_float2(red[0] + red[1] + red[2] + red[3],
                        red[4] + red[5] + red[6] + red[7]);
}

__global__ __launch_bounds__(256) void prep_kernel(const float* __restrict__ x,
                                                   float2* __restrict__ part,
                                                   const float* __restrict__ w0,
                                                   const float* __restrict__ w1,
                                                   const float* __restrict__ w2,
                                                   const float* __restrict__ w3,
                                                   unsigned short* __restrict__ wb) {
    __shared__ float red[8];
    int bx = blockIdx.x, t = threadIdx.x;
    if (bx < 512) {
        stats_body(x, part, red, bx, t);
    } else {
        int chunk = bx - 512;
        int w = chunk >> 8;
        const float* sp = (w == 0) ? w0 : (w == 1) ? w1 : (w == 2) ? w2 : w3;
        unsigned short* o = wb + (size_t)w * 262144;
        int idx = (chunk & 255) * 256 + t;
        float4 v = ((const float4*)sp)[idx];
        ushort4 r;
        r.x = f2bf(v.x); r.y = f2bf(v.y); r.z = f2bf(v.z); r.w = f2bf(v.w);
        ((ushort4*)o)[idx] = r;
    }
}

// -------- GN apply + transposed write: x[b,c,hw] f32 -> hT[b,hw,c] bf16 -----
__global__ __launch_bounds__(256) void gn_applyT(const float* __restrict__ x,
                                                 const float2* __restrict__ part,
                                                 const float* __restrict__ gs,
                                                 const float* __restrict__ gb,
                                                 unsigned short* __restrict__ hT) {
    __shared__ unsigned short tile[128 * 66];
    int bx = blockIdx.x, t = threadIdx.x;
    int b = bx & 7, g = (bx >> 3) & 7, ic = bx >> 6;
    int bg = b * 8 + g;
    float s = 0.f, q = 0.f;
#pragma unroll
    for (int k = 0; k < 8; ++k) { float2 p = part[bg * 8 + k]; s += p.x; q += p.y; }
    float mean = s * (1.f / 65536.f);
    float var = q * (1.f / 65536.f) - mean * mean;
    float rstd = rsqrtf(var + 1e-5f);

    int i4 = t & 31, cq = t >> 5;
    size_t xbase = ((size_t)b * 512 + g * 64) * 1024 + ic * 128;
#pragma unroll
    for (int pass = 0; pass < 8; ++pass) {
        int c = pass * 8 + cq;
        float4 v = *(const float4*)&x[xbase + (size_t)c * 1024 + i4 * 4];
        int gc = g * 64 + c;
        float sc = gs[gc] * rstd, bi = gb[gc] - mean * sc;
        unsigned short* tp = &tile[(i4 * 4) * 66 + c];
        tp[0]   = f2bf(v.x * sc + bi);
        tp[66]  = f2bf(v.y * sc + bi);
        tp[132] = f2bf(v.z * sc + bi);
        tp[198] = f2bf(v.w * sc + bi);
    }
    __syncthreads();
    int i = t >> 1, h = t & 1;
    const unsigned short* tp2 = &tile[i * 66 + h * 32];
    unsigned short* op = &hT[(size_t)b * (1024 * 512) + (size_t)(ic * 128 + i) * 512 + g * 64 + h * 32];
#pragma unroll
    for (int cc = 0; cc < 4; ++cc) {
        unsigned short tmp[8];
#pragma unroll
        for (int j = 0; j < 8; ++j) tmp[j] = tp2[cc * 8 + j];
        *(uint4*)&op[cc * 8] = *(const uint4*)tmp;
    }
}

template <int TM, int MODE, int MINW, int PIPE>
__global__ __launch_bounds__(256, MINW) void gemm_bt(
        const unsigned short* __restrict__ A, const unsigned short* __restrict__ B,
        const float* __restrict__ b0, const float* __restrict__ b1,
        const float* __restrict__ b2,
        void* __restrict__ C0, void* __restrict__ C1, void* __restrict__ C2,
        const float* __restrict__ resid, float* __restrict__ spart,
        int M, int N, int K, float scale, size_t sA, size_t sB, size_t sC) {
    constexpr int NBUF = PIPE ? 2 : 1;
    __shared__ __align__(16) unsigned short As[NBUF * TM * 64];
    __shared__ __align__(16) unsigned short Bs[NBUF * 128 * 64];
    gemm_phase<TM, MODE, PIPE>(As, Bs, A, B, b0, b1, b2, C0, C1, C2, resid, spart,
                               M, N, K, scale, sA, sB, sC, blockIdx.x, threadIdx.x);
}

extern "C" void kernel_launch(void* const* d_in, const int* in_sizes, int n_in,
                              void* d_out, int out_size, void* d_ws, size_t ws_size,
                              hipStream_t stream) {
    const float* x  = (const float*)d_in[0];
    const float* gs = (const float*)d_in[1];
    const float* gb = (const float*)d_in[2];
    const float* wq = (const float*)d_in[3];
    const float* bq = (const float*)d_in[4];
    const float* wk = (const float*)d_in[5];
    const float* bk = (const float*)d_in[6];
    const float* wv = (const float*)d_in[7];
    const float* bv = (const float*)d_in[8];
    const float* wp = (const float*)d_in[9];
    const float* bp = (const float*)d_in[10];
    float* out = (float*)d_out;

    char* ws = (char*)d_ws;
    const size_t MB = 1u << 20;
    unsigned short* hT = (unsigned short*)(ws + 0);         // [b][1024][512]
    unsigned short* wb = (unsigned short*)(ws + 8 * MB);    // [wq;wk;wv;wp] bf16
    unsigned short* qT = (unsigned short*)(ws + 10 * MB);   // [b][1024][512]
    unsigned short* kT = (unsigned short*)(ws + 18 * MB);   // [b][1024][512]
    unsigned short* vN = (unsigned short*)(ws + 26 * MB);   // [b][512][1024]
    unsigned short* E  = (unsigned short*)(ws + 34 * MB);   // [b][1024][1024] bf16
    unsigned short* OT = (unsigned short*)(ws + 50 * MB);   // [b][1024][512]
    float2* gnpart     = (float2*)(ws + 58 * MB);           // 512 x float2
    float*  spart      = (float*)(ws + 58 * MB + 65536);    // [b][16][1024] f32 (by i)

    const unsigned short* wpb = wb + 3 * 262144;
    const size_t sH = 1024 * 512;
    const size_t sS = 1024 * 1024;

    prep_kernel<<<1536, 256, 0, stream>>>(x, gnpart, wq, wk, wv, wp, wb);
    gn_applyT<<<512, 256, 0, stream>>>(x, gnpart, gs, gb, hT);

    // QKV fused: TM=128, 1-phase, 768 blocks = 3/CU; V tiles dispatched first,
    // Q/K last; all outputs written via full-line re-tile flush.
    gemm_bt<128, 0, 3, 0><<<768, 256, 0, stream>>>(
        wb, hT, bq, bk, bv, qT, kT, vN, nullptr, nullptr,
        1536, 1024, 512, 1.f, 0, sH, sH);
    // scores: A=qT, B=kT -> E[i][j] natural via full-line re-tile flush
    // + spart by i-row. TM=128, 2-phase, 512 blocks.
    gemm_bt<128, 1, 2, 1><<<512, 256, 0, stream>>>(
        qT, kT, nullptr, nullptr, nullptr, E, nullptr, nullptr, nullptr, spart,
        1024, 1024, 512, 0.044194173824159216f, sH, sH, sS);
    // PV: A=vN, B=E -> OT[i][c] (C^T), normalized by rowsum; 2-phase
    gemm_bt<64, 2, 2, 1><<<512, 256, 0, stream>>>(
        vN, E, nullptr, nullptr, nullptr, OT, nullptr, nullptr, nullptr, spart,
        512, 1024, 1024, 1.f, sH, sS, sH);
    // proj: A=OT, B=Wp -> out[b][c][i] f32 (C^T) + bias[c] + resid
    gemm_bt<64, 3, 2, 1><<<512, 256, 0, stream>>>(
        OT, wpb, bp, nullptr, nullptr, out, nullptr, nullptr, x, nullptr,
        1024, 512, 512, 1.f, sH, 0, sH);
}